// Round 1
// baseline (1563.045 us; speedup 1.0000x reference)
//
#include <hip/hip_runtime.h>
#include <math.h>

#define BB 4
#define NN 2048
#define MM 2048
#define DIM 512
#define HEADS 8
#define DH 64
#define INNER 512
#define NEGV (-1.0e30f)

// ---------------------------------------------------------------------------
// Tiled fp32 GEMM: C = A[nrows x K] @ W[K x NC], 64x64 tile, BK=16, 256 thr.
// MODE 0: Q proj   -> out0[(b,h,n,d)] = tanh(acc) * 0.125
// MODE 1: KV proj  -> col<512: out0[(b,h,m,d)] = tanh(acc) (K)
//                     col>=512: out1[(b,h,m,d)] = acc       (V)
// MODE 2: final    -> out0[row*512+col] = acc + bias[col]
// ---------------------------------------------------------------------------
template<int MODE>
__launch_bounds__(256)
__global__ void gemm_k(const float* __restrict__ A, const float* __restrict__ W,
                       float* __restrict__ out0, float* __restrict__ out1,
                       const float* __restrict__ bias, int K, int NC)
{
    __shared__ float sA[16][65];
    __shared__ float sB[16][65];
    const int tid  = threadIdx.x;
    const int row0 = blockIdx.x * 64;
    const int col0 = blockIdx.y * 64;
    const int tx = tid & 15, ty = tid >> 4;
    const int ar = tid >> 2;        // 0..63
    const int ak = (tid & 3) * 4;   // 0,4,8,12
    const int bk = tid >> 4;        // 0..15
    const int bn = (tid & 15) * 4;  // 0..60

    float acc[4][4] = {};

    for (int k0 = 0; k0 < K; k0 += 16) {
        float4 av = *(const float4*)(A + (size_t)(row0 + ar) * K + k0 + ak);
        float4 bv = *(const float4*)(W + (size_t)(k0 + bk) * NC + col0 + bn);
        __syncthreads();
        sA[ak + 0][ar] = av.x; sA[ak + 1][ar] = av.y;
        sA[ak + 2][ar] = av.z; sA[ak + 3][ar] = av.w;
        sB[bk][bn + 0] = bv.x; sB[bk][bn + 1] = bv.y;
        sB[bk][bn + 2] = bv.z; sB[bk][bn + 3] = bv.w;
        __syncthreads();
#pragma unroll
        for (int kk = 0; kk < 16; kk++) {
            float a[4], b[4];
#pragma unroll
            for (int i = 0; i < 4; i++) a[i] = sA[kk][ty * 4 + i];
#pragma unroll
            for (int j = 0; j < 4; j++) b[j] = sB[kk][tx * 4 + j];
#pragma unroll
            for (int i = 0; i < 4; i++)
#pragma unroll
                for (int j = 0; j < 4; j++)
                    acc[i][j] += a[i] * b[j];
        }
    }

#pragma unroll
    for (int i = 0; i < 4; i++) {
        const int row = row0 + ty * 4 + i;
        const int bidx = row >> 11;        // row / 2048
        const int nidx = row & 2047;
#pragma unroll
        for (int j = 0; j < 4; j++) {
            const int col = col0 + tx * 4 + j;
            if (MODE == 0) {
                const int h = col >> 6, d = col & 63;
                out0[(((size_t)bidx * HEADS + h) * NN + nidx) * DH + d] =
                    tanhf(acc[i][j]) * 0.125f;
            } else if (MODE == 1) {
                if (col < INNER) {
                    const int h = col >> 6, d = col & 63;
                    out0[(((size_t)bidx * HEADS + h) * MM + nidx) * DH + d] =
                        tanhf(acc[i][j]);
                } else {
                    const int c = col - INNER;
                    const int h = c >> 6, d = c & 63;
                    out1[(((size_t)bidx * HEADS + h) * MM + nidx) * DH + d] =
                        acc[i][j];
                }
            } else {
                out0[(size_t)row * 512 + col] = acc[i][j] + bias[col];
            }
        }
    }
}

// ---------------------------------------------------------------------------
// Flash attention, fp32. Block = (bh, 32-query tile). 256 threads.
// thread: rr = tid>>4 owns rows rr and rr+16; sub = tid&15 owns 4 j's / 4 d's.
// Null token folded into online-softmax init.
// ---------------------------------------------------------------------------
__launch_bounds__(256)
__global__ void attn_k(const float* __restrict__ qws, const float* __restrict__ kws,
                       const float* __restrict__ vws,
                       const int* __restrict__ mask, const int* __restrict__ cmask,
                       const float* __restrict__ null_key,
                       const float* __restrict__ null_value,
                       float* __restrict__ ows)
{
    __shared__ float sQ[32][65];
    __shared__ float sK[64][65];
    __shared__ float sV[64][65];
    __shared__ float sP[64][33];
    __shared__ float sNK[64];
    __shared__ float sNV[64];

    const int tid = threadIdx.x;
    const int bh  = blockIdx.x;          // 0..31
    const int q0  = blockIdx.y * 32;
    const int b   = bh >> 3;
    const int h   = bh & 7;
    const int sub = tid & 15;
    const int rr  = tid >> 4;            // 0..15
    const int r0 = rr, r1 = rr + 16;

    // Q tile (32x64)
    for (int f = tid; f < 512; f += 256) {
        const int r = f >> 4, c = (f & 15) * 4;
        float4 v = *(const float4*)(qws + ((size_t)bh * NN + q0 + r) * DH + c);
        sQ[r][c] = v.x; sQ[r][c + 1] = v.y; sQ[r][c + 2] = v.z; sQ[r][c + 3] = v.w;
    }
    if (tid < 64) {
        sNK[tid] = tanhf(null_key[tid]);
        sNV[tid] = null_value[tid];
    }
    const int rowOk0 = mask[(size_t)b * NN + q0 + r0];
    const int rowOk1 = mask[(size_t)b * NN + q0 + r1];
    __syncthreads();

    // null-token init
    float pn0 = 0.f, pn1 = 0.f;
#pragma unroll
    for (int dd = 0; dd < 4; dd++) {
        const int d = sub * 4 + dd;
        pn0 += sQ[r0][d] * sNK[d];
        pn1 += sQ[r1][d] * sNK[d];
    }
#pragma unroll
    for (int w = 1; w < 16; w <<= 1) {
        pn0 += __shfl_xor(pn0, w, 16);
        pn1 += __shfl_xor(pn1, w, 16);
    }
    float m0 = rowOk0 ? pn0 : NEGV;
    float m1 = rowOk1 ? pn1 : NEGV;
    float l0 = 1.f, l1 = 1.f;
    float O0[4], O1[4];
#pragma unroll
    for (int dd = 0; dd < 4; dd++) {
        O0[dd] = sNV[sub * 4 + dd];
        O1[dd] = sNV[sub * 4 + dd];
    }

    for (int jc = 0; jc < MM; jc += 64) {
        for (int f = tid; f < 1024; f += 256) {
            const int r = f >> 4, c = (f & 15) * 4;
            float4 kv = *(const float4*)(kws + ((size_t)bh * MM + jc + r) * DH + c);
            float4 vv = *(const float4*)(vws + ((size_t)bh * MM + jc + r) * DH + c);
            sK[r][c] = kv.x; sK[r][c + 1] = kv.y; sK[r][c + 2] = kv.z; sK[r][c + 3] = kv.w;
            sV[r][c] = vv.x; sV[r][c + 1] = vv.y; sV[r][c + 2] = vv.z; sV[r][c + 3] = vv.w;
        }
        const int4 cmv = *(const int4*)(cmask + (size_t)b * MM + jc + sub * 4);
        __syncthreads();

        float s0[4] = {0, 0, 0, 0}, s1[4] = {0, 0, 0, 0};
        for (int d = 0; d < 64; d++) {
            const float qa = sQ[r0][d], qb = sQ[r1][d];
#pragma unroll
            for (int jj = 0; jj < 4; jj++) {
                const float kv = sK[sub * 4 + jj][d];
                s0[jj] += qa * kv;
                s1[jj] += qb * kv;
            }
        }
        const int cm[4] = {cmv.x, cmv.y, cmv.z, cmv.w};
        float cmax0 = NEGV, cmax1 = NEGV;
#pragma unroll
        for (int jj = 0; jj < 4; jj++) {
            s0[jj] = (rowOk0 && cm[jj]) ? s0[jj] : NEGV;
            s1[jj] = (rowOk1 && cm[jj]) ? s1[jj] : NEGV;
            cmax0 = fmaxf(cmax0, s0[jj]);
            cmax1 = fmaxf(cmax1, s1[jj]);
        }
#pragma unroll
        for (int w = 1; w < 16; w <<= 1) {
            cmax0 = fmaxf(cmax0, __shfl_xor(cmax0, w, 16));
            cmax1 = fmaxf(cmax1, __shfl_xor(cmax1, w, 16));
        }
        const float mN0 = fmaxf(m0, cmax0);
        const float mN1 = fmaxf(m1, cmax1);
        float p0[4], p1[4];
        float cs0 = 0.f, cs1 = 0.f;
#pragma unroll
        for (int jj = 0; jj < 4; jj++) {
            p0[jj] = expf(s0[jj] - mN0); cs0 += p0[jj];
            p1[jj] = expf(s1[jj] - mN1); cs1 += p1[jj];
        }
#pragma unroll
        for (int w = 1; w < 16; w <<= 1) {
            cs0 += __shfl_xor(cs0, w, 16);
            cs1 += __shfl_xor(cs1, w, 16);
        }
        const float a0 = expf(m0 - mN0);
        const float a1 = expf(m1 - mN1);
        l0 = l0 * a0 + cs0;
        l1 = l1 * a1 + cs1;
        m0 = mN0; m1 = mN1;
#pragma unroll
        for (int dd = 0; dd < 4; dd++) { O0[dd] *= a0; O1[dd] *= a1; }
#pragma unroll
        for (int jj = 0; jj < 4; jj++) {
            sP[sub * 4 + jj][r0] = p0[jj];
            sP[sub * 4 + jj][r1] = p1[jj];
        }
        __syncthreads();

        for (int j = 0; j < 64; j++) {
            const float w0 = sP[j][r0], w1 = sP[j][r1];
#pragma unroll
            for (int dd = 0; dd < 4; dd++) {
                const float vv = sV[j][sub * 4 + dd];
                O0[dd] += w0 * vv;
                O1[dd] += w1 * vv;
            }
        }
        __syncthreads();
    }

    const float inv0 = 1.f / l0, inv1 = 1.f / l1;
#pragma unroll
    for (int dd = 0; dd < 4; dd++) {
        ows[(((size_t)b * NN + q0 + r0) * HEADS + h) * DH + sub * 4 + dd] = O0[dd] * inv0;
        ows[(((size_t)b * NN + q0 + r1) * HEADS + h) * DH + sub * 4 + dd] = O1[dd] * inv1;
    }
}

extern "C" void kernel_launch(void* const* d_in, const int* in_sizes, int n_in,
                              void* d_out, int out_size, void* d_ws, size_t ws_size,
                              hipStream_t stream)
{
    const float* x    = (const float*)d_in[0];
    const float* ctx  = (const float*)d_in[1];
    const int*   mask = (const int*)d_in[2];
    const int*   cmsk = (const int*)d_in[3];
    const float* Wq   = (const float*)d_in[4];
    const float* Wkv  = (const float*)d_in[5];
    const float* Wo   = (const float*)d_in[6];
    const float* bo   = (const float*)d_in[7];
    const float* nk   = (const float*)d_in[8];
    const float* nv   = (const float*)d_in[9];
    float* out = (float*)d_out;

    const size_t S = (size_t)BB * HEADS * NN * DH;  // 4,194,304 floats
    float* qws = (float*)d_ws;
    float* kws = qws + S;
    float* vws = kws + S;
    float* ows = vws + S;

    dim3 blk(256);
    gemm_k<0><<<dim3(128, 8),  blk, 0, stream>>>(x,   Wq,  qws, nullptr, nullptr, DIM, INNER);
    gemm_k<1><<<dim3(128, 16), blk, 0, stream>>>(ctx, Wkv, kws, vws,     nullptr, DIM, 2 * INNER);
    attn_k<<<dim3(32, 64), blk, 0, stream>>>(qws, kws, vws, mask, cmsk, nk, nv, ows);
    gemm_k<2><<<dim3(128, 8),  blk, 0, stream>>>(ows, Wo,  out, nullptr, bo,      INNER, 512);
}

// Round 3
// 518.207 us; speedup vs baseline: 3.0163x; 3.0163x over previous
//
#include <hip/hip_runtime.h>
#include <math.h>

#define BB 4
#define NN 2048
#define MM 2048
#define DIM 512
#define HEADS 8
#define DH 64
#define INNER 512

typedef _Float16 f16;
typedef _Float16 f16x8 __attribute__((ext_vector_type(8)));
typedef _Float16 f16x4 __attribute__((ext_vector_type(4)));
typedef float f32x4 __attribute__((ext_vector_type(4)));

// ---------------------------------------------------------------------------
// Tiled fp32 GEMM: C = A[nrows x K] @ W[K x NC], 64x64 tile, BK=16, 256 thr.
// MODE 0: Q proj  -> qws f16 [bh][n][d] = tanh(acc)*0.125
// MODE 1: KV proj -> col<512:  kws f16 [bh][m][d] = tanh(acc)
//                    col>=512: vtws f16 [bh][d][m] = acc   (TRANSPOSED via LDS)
// MODE 2: final   -> o32[row*512+col] = acc + bias[col]
// ---------------------------------------------------------------------------
template<int MODE>
__launch_bounds__(256)
__global__ void gemm_k(const float* __restrict__ A, const float* __restrict__ W,
                       f16* __restrict__ o16a, f16* __restrict__ o16b,
                       float* __restrict__ o32, const float* __restrict__ bias,
                       int K, int NC)
{
    __shared__ float sA[16][65];
    __shared__ float sB[16][65];
    __shared__ f16 T[(MODE == 1) ? 64 * 72 : 1];

    const int tid  = threadIdx.x;
    const int row0 = blockIdx.x * 64;
    const int col0 = blockIdx.y * 64;
    const int tx = tid & 15, ty = tid >> 4;
    const int ar = tid >> 2;
    const int ak = (tid & 3) * 4;
    const int bk = tid >> 4;
    const int bn = (tid & 15) * 4;

    float acc[4][4] = {};

    for (int k0 = 0; k0 < K; k0 += 16) {
        float4 av = *(const float4*)(A + (size_t)(row0 + ar) * K + k0 + ak);
        float4 bv = *(const float4*)(W + (size_t)(k0 + bk) * NC + col0 + bn);
        __syncthreads();
        sA[ak + 0][ar] = av.x; sA[ak + 1][ar] = av.y;
        sA[ak + 2][ar] = av.z; sA[ak + 3][ar] = av.w;
        sB[bk][bn + 0] = bv.x; sB[bk][bn + 1] = bv.y;
        sB[bk][bn + 2] = bv.z; sB[bk][bn + 3] = bv.w;
        __syncthreads();
#pragma unroll
        for (int kk = 0; kk < 16; kk++) {
            float a[4], b[4];
#pragma unroll
            for (int i = 0; i < 4; i++) a[i] = sA[kk][ty * 4 + i];
#pragma unroll
            for (int j = 0; j < 4; j++) b[j] = sB[kk][tx * 4 + j];
#pragma unroll
            for (int i = 0; i < 4; i++)
#pragma unroll
                for (int j = 0; j < 4; j++)
                    acc[i][j] += a[i] * b[j];
        }
    }

    const int bidx = row0 >> 11;
    const int m0   = row0 & 2047;

    if (MODE == 0) {
        const int h = col0 >> 6;
#pragma unroll
        for (int i = 0; i < 4; i++) {
            const int nidx = m0 + ty * 4 + i;
            f16x4 pk;
#pragma unroll
            for (int j = 0; j < 4; j++) pk[j] = (f16)(tanhf(acc[i][j]) * 0.125f);
            *(f16x4*)(o16a + (((size_t)bidx * HEADS + h) * NN + nidx) * DH + tx * 4) = pk;
        }
    } else if (MODE == 1) {
        if (col0 < INNER) {      // K columns
            const int h = col0 >> 6;
#pragma unroll
            for (int i = 0; i < 4; i++) {
                const int nidx = m0 + ty * 4 + i;
                f16x4 pk;
#pragma unroll
                for (int j = 0; j < 4; j++) pk[j] = (f16)tanhf(acc[i][j]);
                *(f16x4*)(o16a + (((size_t)bidx * HEADS + h) * MM + nidx) * DH + tx * 4) = pk;
            }
        } else {                 // V columns -> transpose to [bh][d][m]
            const int hv = (col0 >> 6) - 8;
#pragma unroll
            for (int i = 0; i < 4; i++)
#pragma unroll
                for (int j = 0; j < 4; j++)
                    T[(tx * 4 + j) * 72 + ty * 4 + i] = (f16)acc[i][j];
            __syncthreads();
            const int d  = tid >> 2;       // 0..63
            const int mc = (tid & 3) * 16;  // 16 halves (32 B) per thread
            uint4 w0 = *(const uint4*)(&T[d * 72 + mc]);
            uint4 w1 = *(const uint4*)(&T[d * 72 + mc + 8]);
            f16* dst = o16b + ((size_t)(bidx * HEADS + hv) * DH + d) * MM + m0 + mc;
            *(uint4*)(dst)     = w0;
            *(uint4*)(dst + 8) = w1;
        }
    } else {
#pragma unroll
        for (int i = 0; i < 4; i++) {
            const int row = row0 + ty * 4 + i;
#pragma unroll
            for (int j = 0; j < 4; j++) {
                const int col = col0 + tx * 4 + j;
                o32[(size_t)row * 512 + col] = acc[i][j] + bias[col];
            }
        }
    }
}

// ---------------------------------------------------------------------------
// MFMA fp16 flash attention, fixed-shift softmax p = exp(s - 2).
// |q|<=0.125, |k|<=1 -> |s|<=8 -> p in [exp(-10), exp(6)], f16-safe, no
// online max needed. Block = 256 thr = 4 waves; wave owns 32 rows; j-tile 64.
// Null token folded into l/O init. Dead rows -> p = 1 (uniform over 2049).
// ---------------------------------------------------------------------------
__launch_bounds__(256)
__global__ void attn_k(const f16* __restrict__ qws, const f16* __restrict__ kws,
                       const f16* __restrict__ vtws,
                       const int* __restrict__ mask, const int* __restrict__ cmask,
                       const float* __restrict__ nk, const float* __restrict__ nv,
                       float* __restrict__ ows)
{
    __shared__ f16 sK[64 * 72];      // [j][d], stride 72 halves
    __shared__ f16 sV[64 * 72];      // [d][j], stride 72 halves
    __shared__ f16 sP[4][32 * 72];   // per-wave [row][j]

    const int tid  = threadIdx.x;
    const int wave = tid >> 6, lane = tid & 63;
    const int l15  = lane & 15, quad = lane >> 4;
    const int bh = blockIdx.x, b = bh >> 3, h = bh & 7;
    const int q0 = blockIdx.y * 128 + wave * 32;

    // Q A-fragments (held for the whole pass)
    f16x8 qf[2][2];
    const f16* qbase = qws + ((size_t)bh * NN + q0) * DH;
#pragma unroll
    for (int rt = 0; rt < 2; rt++)
#pragma unroll
        for (int ks = 0; ks < 2; ks++)
            qf[rt][ks] = *(const f16x8*)(qbase + (rt * 16 + l15) * DH + ks * 32 + quad * 8);

    // null-key sim per row (row indexed by l15 after quad-reduce)
    float pn[2] = {0.f, 0.f};
#pragma unroll
    for (int ks = 0; ks < 2; ks++)
#pragma unroll
        for (int t = 0; t < 8; t++) {
            float nkt = tanhf(nk[ks * 32 + quad * 8 + t]);
            pn[0] += (float)qf[0][ks][t] * nkt;
            pn[1] += (float)qf[1][ks][t] * nkt;
        }
#pragma unroll
    for (int rt = 0; rt < 2; rt++) {
        pn[rt] += __shfl_xor(pn[rt], 16);
        pn[rt] += __shfl_xor(pn[rt], 32);
    }

    float nvv[4];
#pragma unroll
    for (int ds = 0; ds < 4; ds++) nvv[ds] = nv[ds * 16 + l15];

    int   rowOk[2][4];
    float l[2][4];
    f32x4 acc[2][4];   // [rt][ds]: row quad*4+reg (+rt*16), col ds*16+l15
#pragma unroll
    for (int rt = 0; rt < 2; rt++)
#pragma unroll
        for (int reg = 0; reg < 4; reg++) {
            const int r = rt * 16 + quad * 4 + reg;
            rowOk[rt][reg] = mask[(size_t)b * NN + q0 + r];
            float pr = __shfl(pn[rt], quad * 4 + reg, 16);
            float pe = __expf(pr - 2.0f);
            float pnull = rowOk[rt][reg] ? pe : 1.0f;
            l[rt][reg] = pnull;
#pragma unroll
            for (int ds = 0; ds < 4; ds++)
                acc[rt][ds][reg] = pnull * nvv[ds];
        }

    const f16* kg0 = kws + (size_t)bh * MM * DH;
    const f16* vg0 = vtws + (size_t)bh * DH * MM;
    const int sr = tid >> 2;          // staging row 0..63
    const int sc = (tid & 3) * 16;    // 16-half (32 B) chunk per thread

    for (int jc = 0; jc < MM; jc += 64) {
        // prefetch into registers (overlaps previous compute)
        uint4 kvr0 = *(const uint4*)(kg0 + (size_t)(jc + sr) * DH + sc);
        uint4 kvr1 = *(const uint4*)(kg0 + (size_t)(jc + sr) * DH + sc + 8);
        uint4 vvr0 = *(const uint4*)(vg0 + (size_t)sr * MM + jc + sc);
        uint4 vvr1 = *(const uint4*)(vg0 + (size_t)sr * MM + jc + sc + 8);
        int cmv[4];
#pragma unroll
        for (int jj = 0; jj < 4; jj++)
            cmv[jj] = cmask[(size_t)b * MM + jc + jj * 16 + l15];

        __syncthreads();
        *(uint4*)(sK + sr * 72 + sc)     = kvr0;
        *(uint4*)(sK + sr * 72 + sc + 8) = kvr1;
        *(uint4*)(sV + sr * 72 + sc)     = vvr0;
        *(uint4*)(sV + sr * 72 + sc + 8) = vvr1;
        __syncthreads();

        // S = Q K^T
        f32x4 s[2][4] = {};
#pragma unroll
        for (int ks = 0; ks < 2; ks++) {
            f16x8 kb[4];
#pragma unroll
            for (int jj = 0; jj < 4; jj++)
                kb[jj] = *(const f16x8*)(sK + (jj * 16 + l15) * 72 + ks * 32 + quad * 8);
#pragma unroll
            for (int rt = 0; rt < 2; rt++)
#pragma unroll
                for (int jj = 0; jj < 4; jj++)
                    s[rt][jj] = __builtin_amdgcn_mfma_f32_16x16x32_f16(
                        qf[rt][ks], kb[jj], s[rt][jj], 0, 0, 0);
        }

        // p = exp(s - 2), masked; write P to per-wave LDS (A-layout source)
        float rs[2][4] = {};
        f16* spw = sP[wave];
#pragma unroll
        for (int rt = 0; rt < 2; rt++)
#pragma unroll
            for (int jj = 0; jj < 4; jj++)
#pragma unroll
                for (int reg = 0; reg < 4; reg++) {
                    float e = __expf(s[rt][jj][reg] - 2.0f);
                    float p = cmv[jj] ? e : 0.0f;
                    p = rowOk[rt][reg] ? p : 1.0f;
                    rs[rt][reg] += p;
                    spw[(rt * 16 + quad * 4 + reg) * 72 + jj * 16 + l15] = (f16)p;
                }
#pragma unroll
        for (int rt = 0; rt < 2; rt++)
#pragma unroll
            for (int reg = 0; reg < 4; reg++) {
                float v = rs[rt][reg];
                v += __shfl_xor(v, 1, 16);
                v += __shfl_xor(v, 2, 16);
                v += __shfl_xor(v, 4, 16);
                v += __shfl_xor(v, 8, 16);
                l[rt][reg] += v;
            }

        // O += P V   (same-wave LDS round-trip; DS ops are wave-ordered)
#pragma unroll
        for (int ks = 0; ks < 2; ks++) {
            f16x8 pa[2], vb[4];
#pragma unroll
            for (int rt = 0; rt < 2; rt++)
                pa[rt] = *(const f16x8*)(spw + (rt * 16 + l15) * 72 + ks * 32 + quad * 8);
#pragma unroll
            for (int ds = 0; ds < 4; ds++)
                vb[ds] = *(const f16x8*)(sV + (ds * 16 + l15) * 72 + ks * 32 + quad * 8);
#pragma unroll
            for (int rt = 0; rt < 2; rt++)
#pragma unroll
                for (int ds = 0; ds < 4; ds++)
                    acc[rt][ds] = __builtin_amdgcn_mfma_f32_16x16x32_f16(
                        pa[rt], vb[ds], acc[rt][ds], 0, 0, 0);
        }
    }

    // epilogue: O / l -> ows fp32 [b][n][h][d]
#pragma unroll
    for (int rt = 0; rt < 2; rt++) {
        float inv[4];
#pragma unroll
        for (int reg = 0; reg < 4; reg++) inv[reg] = 1.0f / l[rt][reg];
#pragma unroll
        for (int ds = 0; ds < 4; ds++)
#pragma unroll
            for (int reg = 0; reg < 4; reg++) {
                const int r = q0 + rt * 16 + quad * 4 + reg;
                ows[((size_t)(b * NN + r) * HEADS + h) * DH + ds * 16 + l15] =
                    acc[rt][ds][reg] * inv[reg];
            }
    }
}

extern "C" void kernel_launch(void* const* d_in, const int* in_sizes, int n_in,
                              void* d_out, int out_size, void* d_ws, size_t ws_size,
                              hipStream_t stream)
{
    const float* x    = (const float*)d_in[0];
    const float* ctx  = (const float*)d_in[1];
    const int*   mask = (const int*)d_in[2];
    const int*   cmsk = (const int*)d_in[3];
    const float* Wq   = (const float*)d_in[4];
    const float* Wkv  = (const float*)d_in[5];
    const float* Wo   = (const float*)d_in[6];
    const float* bo   = (const float*)d_in[7];
    const float* nk   = (const float*)d_in[8];
    const float* nv   = (const float*)d_in[9];
    float* out = (float*)d_out;

    const size_t S = (size_t)BB * HEADS * NN * DH;  // 4,194,304 elems
    f16* qws  = (f16*)d_ws;
    f16* kws  = qws + S;
    f16* vtws = kws + S;
    float* ows = (float*)(vtws + S);

    dim3 blk(256);
    gemm_k<0><<<dim3(128, 8),  blk, 0, stream>>>(x,   Wq,  qws, nullptr, nullptr, nullptr, DIM, INNER);
    gemm_k<1><<<dim3(128, 16), blk, 0, stream>>>(ctx, Wkv, kws, vtws,    nullptr, nullptr, DIM, 2 * INNER);
    attn_k<<<dim3(32, 16), blk, 0, stream>>>(qws, kws, vtws, mask, cmsk, nk, nv, ows);
    gemm_k<2><<<dim3(128, 8),  blk, 0, stream>>>(ows, Wo,  nullptr, nullptr, out, bo, INNER, 512);
}

// Round 4
// 275.627 us; speedup vs baseline: 5.6709x; 1.8801x over previous
//
#include <hip/hip_runtime.h>
#include <math.h>

#define BB 4
#define NN 2048
#define MM 2048
#define DIM 512
#define HEADS 8
#define DH 64
#define INNER 512

typedef _Float16 f16;
typedef _Float16 f16x8 __attribute__((ext_vector_type(8)));
typedef _Float16 f16x4 __attribute__((ext_vector_type(4)));
typedef float f32x4 __attribute__((ext_vector_type(4)));
typedef short bf16x8v __attribute__((ext_vector_type(8)));
typedef unsigned short ushort;

__device__ __forceinline__ void bsplit(float v, ushort& h, ushort& l) {
    unsigned bits = __float_as_uint(v);
    float res = v - __uint_as_float(bits & 0xffff0000u);
    h = (ushort)(bits >> 16);
    l = (ushort)(__float_as_uint(res) >> 16);
}

// ---------------------------------------------------------------------------
// Elementwise fp32 -> bf16 hi/lo split, same layout. n4 = elems/4.
// ---------------------------------------------------------------------------
__global__ void split_k(const float* __restrict__ in, ushort* __restrict__ hi,
                        ushort* __restrict__ lo, int n4)
{
    int i = blockIdx.x * 256 + threadIdx.x;
    if (i >= n4) return;
    float4 v = ((const float4*)in)[i];
    float e[4] = {v.x, v.y, v.z, v.w};
    ushort hh[4], ll[4];
#pragma unroll
    for (int j = 0; j < 4; j++) bsplit(e[j], hh[j], ll[j]);
    ushort4 h = {hh[0], hh[1], hh[2], hh[3]};
    ushort4 l = {ll[0], ll[1], ll[2], ll[3]};
    ((ushort4*)hi)[i] = h;
    ((ushort4*)lo)[i] = l;
}

// ---------------------------------------------------------------------------
// W [K][N] fp32 -> Wt hi/lo [N][K] bf16 (transpose + split). Tile 32k x 64n.
// ---------------------------------------------------------------------------
__global__ void wsplit_k(const float* __restrict__ W, ushort* __restrict__ Th,
                         ushort* __restrict__ Tl, int K, int N)
{
    __shared__ ushort Sh[64][36], Sl[64][36];
    const int tid = threadIdx.x;
    const int k0 = blockIdx.x * 32, n0 = blockIdx.y * 64;
    const int kr = tid >> 3, nc = (tid & 7) * 8;
    float4 v0 = *(const float4*)(W + (size_t)(k0 + kr) * N + n0 + nc);
    float4 v1 = *(const float4*)(W + (size_t)(k0 + kr) * N + n0 + nc + 4);
    float e[8] = {v0.x, v0.y, v0.z, v0.w, v1.x, v1.y, v1.z, v1.w};
#pragma unroll
    for (int j = 0; j < 8; j++) {
        ushort h, l;
        bsplit(e[j], h, l);
        Sh[nc + j][kr] = h;
        Sl[nc + j][kr] = l;
    }
    __syncthreads();
    const int n = tid >> 2, kc = (tid & 3) * 8;
    *(uint4*)(Th + (size_t)(n0 + n) * K + k0 + kc) = *(const uint4*)(&Sh[n][kc]);
    *(uint4*)(Tl + (size_t)(n0 + n) * K + k0 + kc) = *(const uint4*)(&Sl[n][kc]);
}

// ---------------------------------------------------------------------------
// bf16x2-split MFMA GEMM: C = A[8192 x K] @ Bt^T, Bt is [N][K] bf16 hi/lo.
// Tile 128x64, 4 waves (wave = 32 rows x 64 cols), BK=32, 3 MFMAs per tile.
// MODE 0: qws f16 [bh][n][d] = tanh(acc)*0.125           (N=512, by=head)
// MODE 1: by<8: kws f16 [bh][m][d] = tanh(acc); by>=8: vt f16 [bh][d][m]
// MODE 2: o32[row*512+col] = acc + bias[col]
// ---------------------------------------------------------------------------
template<int MODE>
__launch_bounds__(256)
__global__ void mgemm(const ushort* __restrict__ Ah, const ushort* __restrict__ Al,
                      const ushort* __restrict__ Bh, const ushort* __restrict__ Bl,
                      f16* __restrict__ o16a, f16* __restrict__ o16b,
                      float* __restrict__ o32, const float* __restrict__ bias,
                      int K)
{
    __shared__ ushort sAh[128 * 36], sAl[128 * 36];
    __shared__ ushort sBh[64 * 36],  sBl[64 * 36];

    const int tid  = threadIdx.x;
    const int wave = tid >> 6, lane = tid & 63;
    const int l15  = lane & 15, quad = lane >> 4;
    const size_t r0 = (size_t)blockIdx.x * 128;
    const int c0 = blockIdx.y * 64;

    const int sr = tid >> 2;          // 0..63
    const int sc = (tid & 3) * 8;     // 8-half chunk

    f32x4 acc[2][4] = {};

    for (int k0 = 0; k0 < K; k0 += 32) {
        uint4 ah0 = *(const uint4*)(Ah + (r0 + sr) * K + k0 + sc);
        uint4 ah1 = *(const uint4*)(Ah + (r0 + 64 + sr) * K + k0 + sc);
        uint4 al0 = *(const uint4*)(Al + (r0 + sr) * K + k0 + sc);
        uint4 al1 = *(const uint4*)(Al + (r0 + 64 + sr) * K + k0 + sc);
        uint4 bh  = *(const uint4*)(Bh + (size_t)(c0 + sr) * K + k0 + sc);
        uint4 bl  = *(const uint4*)(Bl + (size_t)(c0 + sr) * K + k0 + sc);
        __syncthreads();
        *(uint4*)(sAh + sr * 36 + sc)        = ah0;
        *(uint4*)(sAh + (64 + sr) * 36 + sc) = ah1;
        *(uint4*)(sAl + sr * 36 + sc)        = al0;
        *(uint4*)(sAl + (64 + sr) * 36 + sc) = al1;
        *(uint4*)(sBh + sr * 36 + sc)        = bh;
        *(uint4*)(sBl + sr * 36 + sc)        = bl;
        __syncthreads();

        bf16x8v a_h[2], a_l[2], b_h[4], b_l[4];
#pragma unroll
        for (int rt = 0; rt < 2; rt++) {
            const int r = wave * 32 + rt * 16 + l15;
            a_h[rt] = *(const bf16x8v*)(sAh + r * 36 + quad * 8);
            a_l[rt] = *(const bf16x8v*)(sAl + r * 36 + quad * 8);
        }
#pragma unroll
        for (int ct = 0; ct < 4; ct++) {
            const int c = ct * 16 + l15;
            b_h[ct] = *(const bf16x8v*)(sBh + c * 36 + quad * 8);
            b_l[ct] = *(const bf16x8v*)(sBl + c * 36 + quad * 8);
        }
#pragma unroll
        for (int rt = 0; rt < 2; rt++)
#pragma unroll
            for (int ct = 0; ct < 4; ct++) {
                acc[rt][ct] = __builtin_amdgcn_mfma_f32_16x16x32_bf16(a_h[rt], b_h[ct], acc[rt][ct], 0, 0, 0);
                acc[rt][ct] = __builtin_amdgcn_mfma_f32_16x16x32_bf16(a_h[rt], b_l[ct], acc[rt][ct], 0, 0, 0);
                acc[rt][ct] = __builtin_amdgcn_mfma_f32_16x16x32_bf16(a_l[rt], b_h[ct], acc[rt][ct], 0, 0, 0);
            }
    }

    const int b    = (int)(r0 >> 11);
    const int rloc = ((int)(r0 & 2047)) + wave * 32;

#pragma unroll
    for (int rt = 0; rt < 2; rt++)
#pragma unroll
        for (int ct = 0; ct < 4; ct++) {
            if (MODE == 0 || (MODE == 1 && blockIdx.y < 8)) {
                const int h = blockIdx.y & 7;
                const int d = ct * 16 + l15;
#pragma unroll
                for (int reg = 0; reg < 4; reg++) {
                    const int n = rloc + rt * 16 + quad * 4 + reg;
                    float v = tanhf(acc[rt][ct][reg]);
                    if (MODE == 0) v *= 0.125f;
                    o16a[(((size_t)b * 8 + h) * 2048 + n) * 64 + d] = (f16)v;
                }
            } else if (MODE == 1) {
                const int h = blockIdx.y - 8;
                const int d = ct * 16 + l15;
                const int m0 = rloc + rt * 16 + quad * 4;
                f16x4 pk;
#pragma unroll
                for (int reg = 0; reg < 4; reg++) pk[reg] = (f16)acc[rt][ct][reg];
                *(f16x4*)(o16b + (((size_t)b * 8 + h) * 64 + d) * 2048 + m0) = pk;
            } else {
                const int col = c0 + ct * 16 + l15;
                const float bv = bias[col];
#pragma unroll
                for (int reg = 0; reg < 4; reg++) {
                    const size_t row = r0 + wave * 32 + rt * 16 + quad * 4 + reg;
                    o32[row * 512 + col] = acc[rt][ct][reg] + bv;
                }
            }
        }
}

// ---------------------------------------------------------------------------
// MFMA fp16 flash attention, fixed-shift softmax p = exp(s - 2).
// Epilogue now writes O as bf16 hi/lo in [b*2048+n][h*64+d] (gemm2 A-layout).
// ---------------------------------------------------------------------------
__launch_bounds__(256)
__global__ void attn_k(const f16* __restrict__ qws, const f16* __restrict__ kws,
                       const f16* __restrict__ vtws,
                       const int* __restrict__ mask, const int* __restrict__ cmask,
                       const float* __restrict__ nk, const float* __restrict__ nv,
                       ushort* __restrict__ oh, ushort* __restrict__ ol)
{
    __shared__ f16 sK[64 * 72];      // [j][d]
    __shared__ f16 sV[64 * 72];      // [d][j]
    __shared__ f16 sP[4][32 * 72];   // per-wave [row][j]

    const int tid  = threadIdx.x;
    const int wave = tid >> 6, lane = tid & 63;
    const int l15  = lane & 15, quad = lane >> 4;
    const int bh = blockIdx.x, b = bh >> 3, h = bh & 7;
    const int q0 = blockIdx.y * 128 + wave * 32;

    f16x8 qf[2][2];
    const f16* qbase = qws + ((size_t)bh * NN + q0) * DH;
#pragma unroll
    for (int rt = 0; rt < 2; rt++)
#pragma unroll
        for (int ks = 0; ks < 2; ks++)
            qf[rt][ks] = *(const f16x8*)(qbase + (rt * 16 + l15) * DH + ks * 32 + quad * 8);

    float pn[2] = {0.f, 0.f};
#pragma unroll
    for (int ks = 0; ks < 2; ks++)
#pragma unroll
        for (int t = 0; t < 8; t++) {
            float nkt = tanhf(nk[ks * 32 + quad * 8 + t]);
            pn[0] += (float)qf[0][ks][t] * nkt;
            pn[1] += (float)qf[1][ks][t] * nkt;
        }
#pragma unroll
    for (int rt = 0; rt < 2; rt++) {
        pn[rt] += __shfl_xor(pn[rt], 16);
        pn[rt] += __shfl_xor(pn[rt], 32);
    }

    float nvv[4];
#pragma unroll
    for (int ds = 0; ds < 4; ds++) nvv[ds] = nv[ds * 16 + l15];

    int   rowOk[2][4];
    float l[2][4];
    f32x4 acc[2][4];
#pragma unroll
    for (int rt = 0; rt < 2; rt++)
#pragma unroll
        for (int reg = 0; reg < 4; reg++) {
            const int r = rt * 16 + quad * 4 + reg;
            rowOk[rt][reg] = mask[(size_t)b * NN + q0 + r];
            float pr = __shfl(pn[rt], quad * 4 + reg, 16);
            float pe = __expf(pr - 2.0f);
            float pnull = rowOk[rt][reg] ? pe : 1.0f;
            l[rt][reg] = pnull;
#pragma unroll
            for (int ds = 0; ds < 4; ds++)
                acc[rt][ds][reg] = pnull * nvv[ds];
        }

    const f16* kg0 = kws + (size_t)bh * MM * DH;
    const f16* vg0 = vtws + (size_t)bh * DH * MM;
    const int sr = tid >> 2;
    const int sc = (tid & 3) * 16;

    for (int jc = 0; jc < MM; jc += 64) {
        uint4 kvr0 = *(const uint4*)(kg0 + (size_t)(jc + sr) * DH + sc);
        uint4 kvr1 = *(const uint4*)(kg0 + (size_t)(jc + sr) * DH + sc + 8);
        uint4 vvr0 = *(const uint4*)(vg0 + (size_t)sr * MM + jc + sc);
        uint4 vvr1 = *(const uint4*)(vg0 + (size_t)sr * MM + jc + sc + 8);
        int cmv[4];
#pragma unroll
        for (int jj = 0; jj < 4; jj++)
            cmv[jj] = cmask[(size_t)b * MM + jc + jj * 16 + l15];

        __syncthreads();
        *(uint4*)(sK + sr * 72 + sc)     = kvr0;
        *(uint4*)(sK + sr * 72 + sc + 8) = kvr1;
        *(uint4*)(sV + sr * 72 + sc)     = vvr0;
        *(uint4*)(sV + sr * 72 + sc + 8) = vvr1;
        __syncthreads();

        f32x4 s[2][4] = {};
#pragma unroll
        for (int ks = 0; ks < 2; ks++) {
            f16x8 kb[4];
#pragma unroll
            for (int jj = 0; jj < 4; jj++)
                kb[jj] = *(const f16x8*)(sK + (jj * 16 + l15) * 72 + ks * 32 + quad * 8);
#pragma unroll
            for (int rt = 0; rt < 2; rt++)
#pragma unroll
                for (int jj = 0; jj < 4; jj++)
                    s[rt][jj] = __builtin_amdgcn_mfma_f32_16x16x32_f16(
                        qf[rt][ks], kb[jj], s[rt][jj], 0, 0, 0);
        }

        float rs[2][4] = {};
        f16* spw = sP[wave];
#pragma unroll
        for (int rt = 0; rt < 2; rt++)
#pragma unroll
            for (int jj = 0; jj < 4; jj++)
#pragma unroll
                for (int reg = 0; reg < 4; reg++) {
                    float e = __expf(s[rt][jj][reg] - 2.0f);
                    float p = cmv[jj] ? e : 0.0f;
                    p = rowOk[rt][reg] ? p : 1.0f;
                    rs[rt][reg] += p;
                    spw[(rt * 16 + quad * 4 + reg) * 72 + jj * 16 + l15] = (f16)p;
                }
#pragma unroll
        for (int rt = 0; rt < 2; rt++)
#pragma unroll
            for (int reg = 0; reg < 4; reg++) {
                float v = rs[rt][reg];
                v += __shfl_xor(v, 1, 16);
                v += __shfl_xor(v, 2, 16);
                v += __shfl_xor(v, 4, 16);
                v += __shfl_xor(v, 8, 16);
                l[rt][reg] += v;
            }

#pragma unroll
        for (int ks = 0; ks < 2; ks++) {
            f16x8 pa[2], vb[4];
#pragma unroll
            for (int rt = 0; rt < 2; rt++)
                pa[rt] = *(const f16x8*)(spw + (rt * 16 + l15) * 72 + ks * 32 + quad * 8);
#pragma unroll
            for (int ds = 0; ds < 4; ds++)
                vb[ds] = *(const f16x8*)(sV + (ds * 16 + l15) * 72 + ks * 32 + quad * 8);
#pragma unroll
            for (int rt = 0; rt < 2; rt++)
#pragma unroll
                for (int ds = 0; ds < 4; ds++)
                    acc[rt][ds] = __builtin_amdgcn_mfma_f32_16x16x32_f16(
                        pa[rt], vb[ds], acc[rt][ds], 0, 0, 0);
        }
    }

#pragma unroll
    for (int rt = 0; rt < 2; rt++) {
        float inv[4];
#pragma unroll
        for (int reg = 0; reg < 4; reg++) inv[reg] = 1.0f / l[rt][reg];
#pragma unroll
        for (int ds = 0; ds < 4; ds++)
#pragma unroll
            for (int reg = 0; reg < 4; reg++) {
                const int r = q0 + rt * 16 + quad * 4 + reg;
                float v = acc[rt][ds][reg] * inv[reg];
                ushort hh, ll;
                bsplit(v, hh, ll);
                size_t idx = ((size_t)(b * 2048 + r)) * 512 + h * 64 + ds * 16 + l15;
                oh[idx] = hh;
                ol[idx] = ll;
            }
    }
}

extern "C" void kernel_launch(void* const* d_in, const int* in_sizes, int n_in,
                              void* d_out, int out_size, void* d_ws, size_t ws_size,
                              hipStream_t stream)
{
    const float* x    = (const float*)d_in[0];
    const float* ctx  = (const float*)d_in[1];
    const int*   mask = (const int*)d_in[2];
    const int*   cmsk = (const int*)d_in[3];
    const float* Wq   = (const float*)d_in[4];
    const float* Wkv  = (const float*)d_in[5];
    const float* Wo   = (const float*)d_in[6];
    const float* bo   = (const float*)d_in[7];
    const float* nk   = (const float*)d_in[8];
    const float* nv   = (const float*)d_in[9];
    float* out = (float*)d_out;

    const size_t S = (size_t)BB * HEADS * NN * DH;  // 4,194,304 elems

    ushort* xh = (ushort*)d_ws;       // aliased as oh after mgemm<0> consumes x
    ushort* xl = xh + S;              // aliased as ol
    ushort* ch = xl + S;
    ushort* cl = ch + S;
    f16* qws = (f16*)(cl + S);
    f16* kws = qws + S;
    f16* vt  = kws + S;
    ushort* wqh  = (ushort*)(vt + S);
    ushort* wql  = wqh + 262144;
    ushort* wkvh = wql + 262144;
    ushort* wkvl = wkvh + 524288;
    ushort* woh  = wkvl + 524288;
    ushort* wol  = woh + 262144;
    ushort* oh = xh;
    ushort* ol = xl;

    dim3 blk(256);
    split_k<<<4096, blk, 0, stream>>>(x,   xh, xl, (int)(S / 4));
    split_k<<<4096, blk, 0, stream>>>(ctx, ch, cl, (int)(S / 4));
    wsplit_k<<<dim3(16, 8),  blk, 0, stream>>>(Wq,  wqh,  wql,  512, 512);
    wsplit_k<<<dim3(16, 16), blk, 0, stream>>>(Wkv, wkvh, wkvl, 512, 1024);
    wsplit_k<<<dim3(16, 8),  blk, 0, stream>>>(Wo,  woh,  wol,  512, 512);
    mgemm<0><<<dim3(64, 8),  blk, 0, stream>>>(xh, xl, wqh,  wql,  qws, nullptr, nullptr, nullptr, 512);
    mgemm<1><<<dim3(64, 16), blk, 0, stream>>>(ch, cl, wkvh, wkvl, kws, vt,      nullptr, nullptr, 512);
    attn_k<<<dim3(32, 16), blk, 0, stream>>>(qws, kws, vt, mask, cmsk, nk, nv, oh, ol);
    mgemm<2><<<dim3(64, 8),  blk, 0, stream>>>(oh, ol, woh,  wol,  nullptr, nullptr, out, bo, 512);
}

// Round 5
// 263.558 us; speedup vs baseline: 5.9306x; 1.0458x over previous
//
#include <hip/hip_runtime.h>
#include <math.h>

#define BB 4
#define NN 2048
#define MM 2048
#define DIM 512
#define HEADS 8
#define DH 64
#define INNER 512

typedef _Float16 f16;
typedef _Float16 f16x8 __attribute__((ext_vector_type(8)));
typedef _Float16 f16x4 __attribute__((ext_vector_type(4)));
typedef float f32x4 __attribute__((ext_vector_type(4)));
typedef short bf16x8v __attribute__((ext_vector_type(8)));
typedef unsigned short ushort;

__device__ __forceinline__ void bsplit(float v, ushort& h, ushort& l) {
    unsigned bits = __float_as_uint(v);
    float res = v - __uint_as_float(bits & 0xffff0000u);
    h = (ushort)(bits >> 16);
    l = (ushort)(__float_as_uint(res) >> 16);
}

// ---------------------------------------------------------------------------
// Elementwise fp32 -> bf16 hi/lo split, same layout. n4 = elems/4.
// ---------------------------------------------------------------------------
__global__ void split_k(const float* __restrict__ in, ushort* __restrict__ hi,
                        ushort* __restrict__ lo, int n4)
{
    int i = blockIdx.x * 256 + threadIdx.x;
    if (i >= n4) return;
    float4 v = ((const float4*)in)[i];
    float e[4] = {v.x, v.y, v.z, v.w};
    ushort hh[4], ll[4];
#pragma unroll
    for (int j = 0; j < 4; j++) bsplit(e[j], hh[j], ll[j]);
    ushort4 h = {hh[0], hh[1], hh[2], hh[3]};
    ushort4 l = {ll[0], ll[1], ll[2], ll[3]};
    ((ushort4*)hi)[i] = h;
    ((ushort4*)lo)[i] = l;
}

// ---------------------------------------------------------------------------
// W [K][N] fp32 -> Wt hi/lo [N][K] bf16 (transpose + split). Tile 32k x 64n.
// ---------------------------------------------------------------------------
__global__ void wsplit_k(const float* __restrict__ W, ushort* __restrict__ Th,
                         ushort* __restrict__ Tl, int K, int N)
{
    __shared__ ushort Sh[64][36], Sl[64][36];
    const int tid = threadIdx.x;
    const int k0 = blockIdx.x * 32, n0 = blockIdx.y * 64;
    const int kr = tid >> 3, nc = (tid & 7) * 8;
    float4 v0 = *(const float4*)(W + (size_t)(k0 + kr) * N + n0 + nc);
    float4 v1 = *(const float4*)(W + (size_t)(k0 + kr) * N + n0 + nc + 4);
    float e[8] = {v0.x, v0.y, v0.z, v0.w, v1.x, v1.y, v1.z, v1.w};
#pragma unroll
    for (int j = 0; j < 8; j++) {
        ushort h, l;
        bsplit(e[j], h, l);
        Sh[nc + j][kr] = h;
        Sl[nc + j][kr] = l;
    }
    __syncthreads();
    const int n = tid >> 2, kc = (tid & 3) * 8;
    *(uint4*)(Th + (size_t)(n0 + n) * K + k0 + kc) = *(const uint4*)(&Sh[n][kc]);
    *(uint4*)(Tl + (size_t)(n0 + n) * K + k0 + kc) = *(const uint4*)(&Sl[n][kc]);
}

// ---------------------------------------------------------------------------
// bf16x2-split MFMA GEMM: C = A[8192 x K] @ Bt^T, Bt is [N][K] bf16 hi/lo.
// Tile 128x64, 4 waves (wave = 32 rows x 64 cols), BK=32, 3 MFMAs per tile.
// MODE 0: qws f16 [bh][n][d] = tanh(acc)*0.125           (N=512, by=head)
// MODE 1: by<8: kws f16 [bh][m][d] = tanh(acc); by>=8: vt f16 [bh][d][m]
// MODE 2: o32[row*512+col] = acc + bias[col]
// ---------------------------------------------------------------------------
template<int MODE>
__launch_bounds__(256)
__global__ void mgemm(const ushort* __restrict__ Ah, const ushort* __restrict__ Al,
                      const ushort* __restrict__ Bh, const ushort* __restrict__ Bl,
                      f16* __restrict__ o16a, f16* __restrict__ o16b,
                      float* __restrict__ o32, const float* __restrict__ bias,
                      int K)
{
    __shared__ ushort sAh[128 * 36], sAl[128 * 36];
    __shared__ ushort sBh[64 * 36],  sBl[64 * 36];

    const int tid  = threadIdx.x;
    const int wave = tid >> 6, lane = tid & 63;
    const int l15  = lane & 15, quad = lane >> 4;
    const size_t r0 = (size_t)blockIdx.x * 128;
    const int c0 = blockIdx.y * 64;

    const int sr = tid >> 2;          // 0..63
    const int sc = (tid & 3) * 8;     // 8-half chunk

    f32x4 acc[2][4] = {};

    for (int k0 = 0; k0 < K; k0 += 32) {
        uint4 ah0 = *(const uint4*)(Ah + (r0 + sr) * K + k0 + sc);
        uint4 ah1 = *(const uint4*)(Ah + (r0 + 64 + sr) * K + k0 + sc);
        uint4 al0 = *(const uint4*)(Al + (r0 + sr) * K + k0 + sc);
        uint4 al1 = *(const uint4*)(Al + (r0 + 64 + sr) * K + k0 + sc);
        uint4 bh  = *(const uint4*)(Bh + (size_t)(c0 + sr) * K + k0 + sc);
        uint4 bl  = *(const uint4*)(Bl + (size_t)(c0 + sr) * K + k0 + sc);
        __syncthreads();
        *(uint4*)(sAh + sr * 36 + sc)        = ah0;
        *(uint4*)(sAh + (64 + sr) * 36 + sc) = ah1;
        *(uint4*)(sAl + sr * 36 + sc)        = al0;
        *(uint4*)(sAl + (64 + sr) * 36 + sc) = al1;
        *(uint4*)(sBh + sr * 36 + sc)        = bh;
        *(uint4*)(sBl + sr * 36 + sc)        = bl;
        __syncthreads();

        bf16x8v a_h[2], a_l[2], b_h[4], b_l[4];
#pragma unroll
        for (int rt = 0; rt < 2; rt++) {
            const int r = wave * 32 + rt * 16 + l15;
            a_h[rt] = *(const bf16x8v*)(sAh + r * 36 + quad * 8);
            a_l[rt] = *(const bf16x8v*)(sAl + r * 36 + quad * 8);
        }
#pragma unroll
        for (int ct = 0; ct < 4; ct++) {
            const int c = ct * 16 + l15;
            b_h[ct] = *(const bf16x8v*)(sBh + c * 36 + quad * 8);
            b_l[ct] = *(const bf16x8v*)(sBl + c * 36 + quad * 8);
        }
#pragma unroll
        for (int rt = 0; rt < 2; rt++)
#pragma unroll
            for (int ct = 0; ct < 4; ct++) {
                acc[rt][ct] = __builtin_amdgcn_mfma_f32_16x16x32_bf16(a_h[rt], b_h[ct], acc[rt][ct], 0, 0, 0);
                acc[rt][ct] = __builtin_amdgcn_mfma_f32_16x16x32_bf16(a_h[rt], b_l[ct], acc[rt][ct], 0, 0, 0);
                acc[rt][ct] = __builtin_amdgcn_mfma_f32_16x16x32_bf16(a_l[rt], b_h[ct], acc[rt][ct], 0, 0, 0);
            }
    }

    const int b    = (int)(r0 >> 11);
    const int rloc = ((int)(r0 & 2047)) + wave * 32;

#pragma unroll
    for (int rt = 0; rt < 2; rt++)
#pragma unroll
        for (int ct = 0; ct < 4; ct++) {
            if (MODE == 0 || (MODE == 1 && blockIdx.y < 8)) {
                const int h = blockIdx.y & 7;
                const int d = ct * 16 + l15;
#pragma unroll
                for (int reg = 0; reg < 4; reg++) {
                    const int n = rloc + rt * 16 + quad * 4 + reg;
                    float v = tanhf(acc[rt][ct][reg]);
                    if (MODE == 0) v *= 0.125f;
                    o16a[(((size_t)b * 8 + h) * 2048 + n) * 64 + d] = (f16)v;
                }
            } else if (MODE == 1) {
                const int h = blockIdx.y - 8;
                const int d = ct * 16 + l15;
                const int m0 = rloc + rt * 16 + quad * 4;
                f16x4 pk;
#pragma unroll
                for (int reg = 0; reg < 4; reg++) pk[reg] = (f16)acc[rt][ct][reg];
                *(f16x4*)(o16b + (((size_t)b * 8 + h) * 64 + d) * 2048 + m0) = pk;
            } else {
                const int col = c0 + ct * 16 + l15;
                const float bv = bias[col];
#pragma unroll
                for (int reg = 0; reg < 4; reg++) {
                    const size_t row = r0 + wave * 32 + rt * 16 + quad * 4 + reg;
                    o32[row * 512 + col] = acc[rt][ct][reg] + bv;
                }
            }
        }
}

// ---------------------------------------------------------------------------
// MFMA fp16 flash attention, transposed-S register trick.
// S^T = K Q^T (C-layout: j=quad*4+reg, r=l15) -> p stays in registers in the
// exact A-operand layout of mfma_f32_16x16x16_f16 for PV. No P LDS.
// Block = 256 thr = 4 waves; wave owns 16 rows; 64 rows/block; grid (32,32).
// Fixed-shift softmax p = exp(s-2) (|s|<=8). Dead rows -> p=1 everywhere.
// Epilogue writes O as bf16 hi/lo (gemm2 A-layout).
// ---------------------------------------------------------------------------
__launch_bounds__(256)
__global__ void attn_k(const f16* __restrict__ qws, const f16* __restrict__ kws,
                       const f16* __restrict__ vtws,
                       const int* __restrict__ mask, const int* __restrict__ cmask,
                       const float* __restrict__ nk, const float* __restrict__ nv,
                       ushort* __restrict__ oh, ushort* __restrict__ ol)
{
    __shared__ f16 sK[64 * 72];      // [j][d]
    __shared__ f16 sV[64 * 72];      // [d][j]
    __shared__ f16 sCM[2048];        // context mask as f16 0/1

    const int tid  = threadIdx.x;
    const int wave = tid >> 6, lane = tid & 63;
    const int l15  = lane & 15, quad = lane >> 4;
    const int bh = blockIdx.x, b = bh >> 3, h = bh & 7;
    const int q0 = blockIdx.y * 64 + wave * 16;

    // context mask -> LDS once per block
    for (int i = tid; i < 2048; i += 256)
        sCM[i] = (f16)(cmask[(size_t)b * MM + i] ? 1.0f : 0.0f);

    // Q fragments: row r = l15 (16 rows per wave)
    f16x8 qf[2];
    const f16* qbase = qws + ((size_t)bh * NN + q0) * DH;
#pragma unroll
    for (int ks = 0; ks < 2; ks++)
        qf[ks] = *(const f16x8*)(qbase + l15 * DH + ks * 32 + quad * 8);

    // null-key sim for row l15
    float pn = 0.f;
#pragma unroll
    for (int ks = 0; ks < 2; ks++)
#pragma unroll
        for (int t = 0; t < 8; t++)
            pn += (float)qf[ks][t] * tanhf(nk[ks * 32 + quad * 8 + t]);
    pn += __shfl_xor(pn, 16);
    pn += __shfl_xor(pn, 32);

    const int rowOkL = mask[(size_t)b * NN + q0 + l15];
    const float pnullL = rowOkL ? __expf(pn - 2.0f) : 1.0f;
    float lrow = pnullL;                 // running denominator for row l15

    // acc[ds]: row = quad*4+reg, col d = ds*16+l15
    f32x4 acc[4];
#pragma unroll
    for (int reg = 0; reg < 4; reg++) {
        const float pa0 = __shfl(pnullL, quad * 4 + reg, 16);
#pragma unroll
        for (int ds = 0; ds < 4; ds++)
            acc[ds][reg] = pa0 * nv[ds * 16 + l15];
    }

    const f16* kg0 = kws + (size_t)bh * MM * DH;
    const f16* vg0 = vtws + (size_t)bh * DH * MM;
    const int sr = tid >> 2;          // 0..63
    const int sc = (tid & 3) * 16;    // 16-half chunk

    for (int jc = 0; jc < MM; jc += 64) {
        uint4 kvr0 = *(const uint4*)(kg0 + (size_t)(jc + sr) * DH + sc);
        uint4 kvr1 = *(const uint4*)(kg0 + (size_t)(jc + sr) * DH + sc + 8);
        uint4 vvr0 = *(const uint4*)(vg0 + (size_t)sr * MM + jc + sc);
        uint4 vvr1 = *(const uint4*)(vg0 + (size_t)sr * MM + jc + sc + 8);

        __syncthreads();
        *(uint4*)(sK + sr * 72 + sc)     = kvr0;
        *(uint4*)(sK + sr * 72 + sc + 8) = kvr1;
        *(uint4*)(sV + sr * 72 + sc)     = vvr0;
        *(uint4*)(sV + sr * 72 + sc + 8) = vvr1;
        __syncthreads();

        // S^T = K Q^T : st[jj] holds S[r=l15][j = jc + jj*16 + quad*4 + reg]
        f32x4 st[4] = {};
#pragma unroll
        for (int ks = 0; ks < 2; ks++) {
#pragma unroll
            for (int jj = 0; jj < 4; jj++) {
                f16x8 kb = *(const f16x8*)(sK + (jj * 16 + l15) * 72 + ks * 32 + quad * 8);
                st[jj] = __builtin_amdgcn_mfma_f32_16x16x32_f16(kb, qf[ks], st[jj], 0, 0, 0);
            }
        }

        // p = exp(s-2) * cm; dead rows -> 1.  P stays in registers (A-layout).
        f16x4 pa[4];
        float rs = 0.f;
#pragma unroll
        for (int jj = 0; jj < 4; jj++) {
            f16x4 cmf = *(const f16x4*)(sCM + jc + jj * 16 + quad * 4);
#pragma unroll
            for (int reg = 0; reg < 4; reg++) {
                float e = __expf(st[jj][reg] - 2.0f);
                float p = e * (float)cmf[reg];
                p = rowOkL ? p : 1.0f;
                rs += p;
                pa[jj][reg] = (f16)p;
            }
        }
        rs += __shfl_xor(rs, 16);
        rs += __shfl_xor(rs, 32);
        lrow += rs;

        // O += P V  (PV via 16x16x16, A = pa directly from registers)
#pragma unroll
        for (int jj = 0; jj < 4; jj++)
#pragma unroll
            for (int ds = 0; ds < 4; ds++) {
                f16x4 vb = *(const f16x4*)(sV + (ds * 16 + l15) * 72 + jj * 16 + quad * 4);
                acc[ds] = __builtin_amdgcn_mfma_f32_16x16x16f16(pa[jj], vb, acc[ds], 0, 0, 0);
            }
    }

    // epilogue: O / l -> bf16 hi/lo, [b*2048+n][h*64+d]
    const float linv = 1.0f / lrow;
#pragma unroll
    for (int reg = 0; reg < 4; reg++) {
        const float inv = __shfl(linv, quad * 4 + reg, 16);
        const int r = q0 + quad * 4 + reg;
#pragma unroll
        for (int ds = 0; ds < 4; ds++) {
            float v = acc[ds][reg] * inv;
            ushort hh, ll;
            bsplit(v, hh, ll);
            size_t idx = ((size_t)(b * 2048 + r)) * 512 + h * 64 + ds * 16 + l15;
            oh[idx] = hh;
            ol[idx] = ll;
        }
    }
}

extern "C" void kernel_launch(void* const* d_in, const int* in_sizes, int n_in,
                              void* d_out, int out_size, void* d_ws, size_t ws_size,
                              hipStream_t stream)
{
    const float* x    = (const float*)d_in[0];
    const float* ctx  = (const float*)d_in[1];
    const int*   mask = (const int*)d_in[2];
    const int*   cmsk = (const int*)d_in[3];
    const float* Wq   = (const float*)d_in[4];
    const float* Wkv  = (const float*)d_in[5];
    const float* Wo   = (const float*)d_in[6];
    const float* bo   = (const float*)d_in[7];
    const float* nk   = (const float*)d_in[8];
    const float* nv   = (const float*)d_in[9];
    float* out = (float*)d_out;

    const size_t S = (size_t)BB * HEADS * NN * DH;  // 4,194,304 elems

    ushort* xh = (ushort*)d_ws;       // aliased as oh after mgemm<0> consumes x
    ushort* xl = xh + S;              // aliased as ol
    ushort* ch = xl + S;
    ushort* cl = ch + S;
    f16* qws = (f16*)(cl + S);
    f16* kws = qws + S;
    f16* vt  = kws + S;
    ushort* wqh  = (ushort*)(vt + S);
    ushort* wql  = wqh + 262144;
    ushort* wkvh = wql + 262144;
    ushort* wkvl = wkvh + 524288;
    ushort* woh  = wkvl + 524288;
    ushort* wol  = woh + 262144;
    ushort* oh = xh;
    ushort* ol = xl;

    dim3 blk(256);
    split_k<<<4096, blk, 0, stream>>>(x,   xh, xl, (int)(S / 4));
    split_k<<<4096, blk, 0, stream>>>(ctx, ch, cl, (int)(S / 4));
    wsplit_k<<<dim3(16, 8),  blk, 0, stream>>>(Wq,  wqh,  wql,  512, 512);
    wsplit_k<<<dim3(16, 16), blk, 0, stream>>>(Wkv, wkvh, wkvl, 512, 1024);
    wsplit_k<<<dim3(16, 8),  blk, 0, stream>>>(Wo,  woh,  wol,  512, 512);
    mgemm<0><<<dim3(64, 8),  blk, 0, stream>>>(xh, xl, wqh,  wql,  qws, nullptr, nullptr, nullptr, 512);
    mgemm<1><<<dim3(64, 16), blk, 0, stream>>>(ch, cl, wkvh, wkvl, kws, vt,      nullptr, nullptr, 512);
    attn_k<<<dim3(32, 32), blk, 0, stream>>>(qws, kws, vt, mask, cmsk, nk, nv, oh, ol);
    mgemm<2><<<dim3(64, 8),  blk, 0, stream>>>(oh, ol, woh,  wol,  nullptr, nullptr, out, bo, 512);
}